// Round 1
// baseline (955.719 us; speedup 1.0000x reference)
//
#include <hip/hip_runtime.h>

#define HIDDEN 5120
#define NEXP 160
#define CHUNK_BYTES 20480           // per 32-k chunk: 160 rows x 64B hi, then 160 x 64B lo
#define NCHUNK 160                  // 5120 / 32
#define WBYTES (CHUNK_BYTES * NCHUNK)   // 3,276,800 B of converted W in ws

typedef _Float16 f16;
typedef f16 f16x8 __attribute__((ext_vector_type(8)));
typedef float f32x4 __attribute__((ext_vector_type(4)));

__device__ __forceinline__ void async_copy16(const void* g, void* l) {
    __builtin_amdgcn_global_load_lds(
        (const __attribute__((address_space(1))) unsigned int*)g,
        (__attribute__((address_space(3))) unsigned int*)l,
        16, 0, 0);
}

// ---------------- K0: W fp32 -> chunked f16 hi/lo (v = hi + lo/2048) ----------------
__global__ void k_convert_w(const float* __restrict__ W, unsigned char* __restrict__ W2) {
    int t = blockIdx.x * 256 + threadIdx.x;        // 102400 threads, 8 k-elems each
    int e  = t / (HIDDEN / 8);
    int k8 = (t - e * (HIDDEN / 8)) * 8;
    const float* src = W + (long)e * HIDDEN + k8;
    float4 v0 = *(const float4*)(src);
    float4 v1 = *(const float4*)(src + 4);
    float v[8] = {v0.x, v0.y, v0.z, v0.w, v1.x, v1.y, v1.z, v1.w};
    f16x8 hi, lo;
#pragma unroll
    for (int j = 0; j < 8; ++j) {
        f16 h = (f16)v[j];
        hi[j] = h;
        lo[j] = (f16)((v[j] - (float)h) * 2048.0f);
    }
    int kc = k8 >> 5;
    int ko = k8 & 31;
    unsigned char* base = W2 + (size_t)kc * CHUNK_BYTES + e * 64 + ko * 2;
    *(f16x8*)base = hi;
    *(f16x8*)(base + 10240) = lo;
}

// ---------------- K1: 3-pass split-f16 MFMA GEMM, fused logits write ----------------
__global__ __launch_bounds__(256, 2)
void k_gemm(const float* __restrict__ X, const unsigned char* __restrict__ W2,
            float* __restrict__ logits) {
    __shared__ __align__(16) unsigned char lds[2 * CHUNK_BYTES];   // 40 KB, double-buffered
    const int tid = threadIdx.x;
    const int w   = tid >> 6;          // wave -> M-tile (16 rows each), BM = 64
    const int l   = tid & 63;
    const int r16 = l & 15;
    const int q   = l >> 4;

    const long rowA = (long)blockIdx.x * 64 + w * 16 + r16;
    const float* aptr = X + rowA * HIDDEN + q * 8;

    const unsigned char* gstage = W2 + (size_t)tid * 16;
    unsigned char* lstage = lds + (tid & ~63) * 16;       // wave-uniform base (+lane*16 by HW)
    const int vb = r16 * 64 + q * 16;                     // B-fragment LDS offset

    f32x4 acc0[10], acc1[10];
    const f32x4 zero = {0.f, 0.f, 0.f, 0.f};
#pragma unroll
    for (int n = 0; n < 10; ++n) { acc0[n] = zero; acc1[n] = zero; }

    // prologue: stage chunk 0 into buf0, prefetch A chunk 0
#pragma unroll
    for (int i = 0; i < 5; ++i)
        async_copy16(gstage + i * 4096, lstage + i * 4096);
    float4 a0 = *(const float4*)(aptr);
    float4 a1 = *(const float4*)(aptr + 4);

#pragma unroll 2
    for (int kc = 0; kc < NCHUNK; ++kc) {
        __syncthreads();   // drains stage(kc)+A(kc) (vmcnt0 at barrier); frees other buffer

        float4 n0 = a0, n1 = a1;
        if (kc + 1 < NCHUNK) {
            const unsigned char* gs = gstage + (size_t)(kc + 1) * CHUNK_BYTES;
            unsigned char* ls = lstage + ((kc + 1) & 1) * CHUNK_BYTES;
#pragma unroll
            for (int i = 0; i < 5; ++i)
                async_copy16(gs + i * 4096, ls + i * 4096);
            n0 = *(const float4*)(aptr + (kc + 1) * 32);
            n1 = *(const float4*)(aptr + (kc + 1) * 32 + 4);
        }

        // convert current A regs -> hi/lo f16 fragments
        float av[8] = {a0.x, a0.y, a0.z, a0.w, a1.x, a1.y, a1.z, a1.w};
        f16x8 ahi, alo;
#pragma unroll
        for (int j = 0; j < 8; ++j) {
            f16 h = (f16)av[j];
            ahi[j] = h;
            alo[j] = (f16)((av[j] - (float)h) * 2048.0f);
        }

        const unsigned char* lb = lds + (kc & 1) * CHUNK_BYTES + vb;
#pragma unroll
        for (int n = 0; n < 10; ++n) {
            f16x8 bhi = *(const f16x8*)(lb + n * 1024);
            f16x8 blo = *(const f16x8*)(lb + n * 1024 + 10240);
            acc0[n] = __builtin_amdgcn_mfma_f32_16x16x32_f16(ahi, bhi, acc0[n], 0, 0, 0);
            acc1[n] = __builtin_amdgcn_mfma_f32_16x16x32_f16(alo, bhi, acc1[n], 0, 0, 0);
            acc1[n] = __builtin_amdgcn_mfma_f32_16x16x32_f16(ahi, blo, acc1[n], 0, 0, 0);
        }
        a0 = n0; a1 = n1;
    }

    // epilogue: logits = acc0 + acc1/2048.  C/D layout: col=lane&15, row=(lane>>4)*4+reg
    const long rowD = (long)blockIdx.x * 64 + w * 16 + q * 4;
    float* orow = logits + rowD * NEXP + r16;
#pragma unroll
    for (int n = 0; n < 10; ++n) {
#pragma unroll
        for (int rr = 0; rr < 4; ++rr) {
            orow[(long)rr * NEXP + n * 16] = acc0[n][rr] + acc1[n][rr] * (1.0f / 2048.0f);
        }
    }
}

// ---------------- K2: softmax denom + group-limited top-6, scaled ----------------
__global__ void k_gate(const float* __restrict__ logits, float* __restrict__ out) {
    const int t = blockIdx.x * 256 + threadIdx.x;
    const float* row = logits + (long)t * NEXP;

    float denom = 0.f;
    float gmax[8];
#pragma unroll
    for (int g = 0; g < 8; ++g) {
        float m = -1e30f;
#pragma unroll
        for (int i = 0; i < 5; ++i) {
            float4 v = *(const float4*)(row + g * 20 + i * 4);
            denom += __expf(v.x) + __expf(v.y) + __expf(v.z) + __expf(v.w);
            m = fmaxf(m, fmaxf(fmaxf(v.x, v.y), fmaxf(v.z, v.w)));
        }
        gmax[g] = m;
    }

    // top-3 groups by group-max logit (softmax is monotone; ties -> lower index, like lax.top_k)
    float b1 = -1e30f, b2 = -1e30f, b3 = -1e30f;
    int i1 = 0, i2 = 0, i3 = 0;
#pragma unroll
    for (int g = 0; g < 8; ++g) {
        float v = gmax[g];
        if (v > b1)      { b3 = b2; i3 = i2; b2 = b1; i2 = i1; b1 = v; i1 = g; }
        else if (v > b2) { b3 = b2; i3 = i2; b2 = v; i2 = g; }
        else if (v > b3) { b3 = v; i3 = g; }
    }

    // top-6 logits among the 3 selected groups (60 candidates, all scores > 0)
    float w6[6] = {-1e30f, -1e30f, -1e30f, -1e30f, -1e30f, -1e30f};
    int gs[3] = {i1, i2, i3};
    for (int gi = 0; gi < 3; ++gi) {
        const float* grp = row + gs[gi] * 20;
#pragma unroll
        for (int i = 0; i < 20; ++i) {
            float v = grp[i];
            if (v > w6[5]) {
                w6[5] = v;
#pragma unroll
                for (int j = 5; j > 0; --j) {
                    if (w6[j] > w6[j - 1]) { float tmp = w6[j - 1]; w6[j - 1] = w6[j]; w6[j] = tmp; }
                }
            }
        }
    }

    float* o = out + (long)t * 6;
#pragma unroll
    for (int j = 0; j < 6; ++j) o[j] = 16.0f * __expf(w6[j]) / denom;
}

extern "C" void kernel_launch(void* const* d_in, const int* in_sizes, int n_in,
                              void* d_out, int out_size, void* d_ws, size_t ws_size,
                              hipStream_t stream) {
    const float* X = (const float*)d_in[0];        // hidden_states [32768, 5120] fp32
    const float* W = (const float*)d_in[1];        // kernel [160, 5120] fp32
    float* out = (float*)d_out;                    // [32768, 6] fp32

    unsigned char* ws = (unsigned char*)d_ws;
    unsigned char* W2 = ws;                        // 3,276,800 B converted W
    float* logits = (float*)(ws + WBYTES);         // 32768*160*4 = 20,971,520 B

    hipLaunchKernelGGL(k_convert_w, dim3(400), dim3(256), 0, stream, W, W2);
    hipLaunchKernelGGL(k_gemm,      dim3(512), dim3(256), 0, stream, X, W2, logits);
    hipLaunchKernelGGL(k_gate,      dim3(128), dim3(256), 0, stream, logits, out);
}